// Round 15
// baseline (149.397 us; speedup 1.0000x reference)
//
#include <hip/hip_runtime.h>
#include <stdint.h>

#define BATCH   32768
#define NSUP    256
#define NSUB    1024
#define LATENT  512
#define NOUT    200
#define SUP_OFF ((size_t)BATCH * NOUT)  // sup_out offset in d_out

typedef unsigned short u16;
typedef __attribute__((ext_vector_type(8))) __bf16 bf16x8;
typedef __attribute__((ext_vector_type(4))) float  floatx4;

typedef const __attribute__((address_space(1))) void* gptr_t;
typedef __attribute__((address_space(3))) void* sptr_t;

__device__ __forceinline__ void gload16(const void* g, void* l) {
  __builtin_amdgcn_global_load_lds((gptr_t)g, (sptr_t)l, 16, 0, 0);
}

__device__ __forceinline__ floatx4 mfma_bf16(bf16x8 a, bf16x8 b, floatx4 c) {
  return __builtin_amdgcn_mfma_f32_16x16x32_bf16(a, b, c, 0, 0, 0);
}

__device__ __forceinline__ u16 f2bf(float f) {
  unsigned int u = __float_as_uint(f);
  u += 0x7FFFu + ((u >> 16) & 1u);   // RNE; inputs finite
  return (u16)(u >> 16);
}

// Bf frag-major layout: col c, k -> group g=c>>4, kc=k>>5, lane=((k>>3)&3)*16 + (c&15), e=k&7
// u16 offset = g*8192 + kc*512 + lane*8 + e. A wave's bv load (16 cols x 32 k) is one
// contiguous 1KB block: lane i reads 16B at base + i*16. No segment splintering.
__device__ __forceinline__ size_t bfoff(int c, int k) {
  return (size_t)(c >> 4) * 8192 + (size_t)((k >> 5) * 512)
       + (size_t)((((k >> 3) & 3) * 16 + (c & 15)) * 8) + (size_t)(k & 7);
}

// ---------------- setup kernel:
// bx [0,320): convert 4 rows each (sup rows 0..255, then sub 0..1023); sub rows written
//   row-major (subs) + frag-major (Bf cols 512..1535)
// bx [320,457): init 35072 min-uints to +inf; bx 457: zero out4
// bx [458,1258): Mt PARTIALS: 800 blocks = 50 o-groups x 2 k-halves x 8 j-chunks;
//   each computes sum_{j in chunk} W[o,j] P[j,k] -> MtF[jc][o][k] (f32, disjoint writes)
// bx [1258,1286): zero Bf cols 400..511
__global__ __launch_bounds__(256) void k_setup(const float* __restrict__ sup,
    const float* __restrict__ sub, const float* __restrict__ W1,
    const float* __restrict__ W2, u16* __restrict__ sups, u16* __restrict__ subs,
    u16* __restrict__ Bf, float* __restrict__ MtF, float* __restrict__ xxsup,
    float* __restrict__ yys, unsigned int* __restrict__ minbuf,
    float* __restrict__ out4) {
  __shared__ float lw[8 * 128];
  int bx = blockIdx.x;
  if (bx >= 458) {
    int idx = bx - 458;
    if (idx >= 800) {            // zero blocks for Bf cols 400..511
      int z = idx - 800;         // 0..27
      int k = (z & 1) * 256 + threadIdx.x;
      int o0 = 400 + (z >> 1) * 8;
      for (int oo = 0; oo < 8; oo++) Bf[bfoff(o0 + oo, k)] = 0;
      return;
    }
    int jc = idx & 7;
    int kb = (idx >> 3) & 1;
    int o0 = (idx >> 4) * 8;     // 0,8,...,392
    int k  = kb * 256 + threadIdx.x;
    const float* P; const float* W; int n, ow, nqs;
    if (o0 < 200) { P = sup; W = W1; n = NSUP;  ow = o0;       nqs = 5; }
    else          { P = sub; W = W2; n = NSUB;  ow = o0 - 200; nqs = 7; }
    int nq = 1 << nqs;           // 32 (sup) or 128 (sub)
    int j0 = jc * nq;
    for (int i = threadIdx.x; i < 8 * nq; i += 256) {
      int oo = i >> nqs, j = i & (nq - 1);
      lw[oo * 128 + j] = W[(size_t)(ow + oo) * n + j0 + j];
    }
    __syncthreads();
    float a[8] = {};
    for (int j = 0; j < nq; j += 8) {          // 8 loads in flight
      float pv[8];
#pragma unroll
      for (int u = 0; u < 8; u++) pv[u] = P[(size_t)(j0 + j + u) * LATENT + k];
#pragma unroll
      for (int oo = 0; oo < 8; oo++) {
        float acc = 0.f;
#pragma unroll
        for (int u = 0; u < 8; u++) acc += pv[u] * lw[oo * 128 + j + u];
        a[oo] += acc;
      }
    }
#pragma unroll
    for (int oo = 0; oo < 8; oo++)
      MtF[((size_t)jc * 400 + o0 + oo) * 512 + k] = a[oo];
    return;
  }
  if (bx >= 320) {
    if (bx == 457) { if (threadIdx.x < 4) out4[threadIdx.x] = 0.f; return; }
    int i = (bx - 320) * 256 + threadIdx.x;
    if (i < BATCH + NSUP + 2 * NSUB) minbuf[i] = 0x7F800000u;
    return;
  }
  int row  = bx * 4 + (threadIdx.x >> 6);
  int lane = threadIdx.x & 63;
  const float* src; u16* dst; float* nrm; int subrow = -1;
  if (row < NSUP) { src = sup + (size_t)row * LATENT; dst = sups + (size_t)row * LATENT; nrm = xxsup + row; }
  else { int r = row - NSUP; subrow = r; src = sub + (size_t)r * LATENT; dst = subs + (size_t)r * LATENT; nrm = yys + r; }
  const float* s = src + lane * 8;
  float4 v0 = ((const float4*)s)[0];
  float4 v1 = ((const float4*)s)[1];
  float ss = v0.x*v0.x + v0.y*v0.y + v0.z*v0.z + v0.w*v0.w
           + v1.x*v1.x + v1.y*v1.y + v1.z*v1.z + v1.w*v1.w;
  uint4 o;
  o.x = (unsigned)f2bf(v0.x) | ((unsigned)f2bf(v0.y) << 16);
  o.y = (unsigned)f2bf(v0.z) | ((unsigned)f2bf(v0.w) << 16);
  o.z = (unsigned)f2bf(v1.x) | ((unsigned)f2bf(v1.y) << 16);
  o.w = (unsigned)f2bf(v1.z) | ((unsigned)f2bf(v1.w) << 16);
  *((uint4*)(dst + lane * 8)) = o;
  if (subrow >= 0) {
    size_t off = (size_t)(32 + (subrow >> 4)) * 8192 + (size_t)((lane >> 2) * 512)
               + (size_t)((((lane & 3) * 16) + (subrow & 15)) * 8);
    *((uint4*)(Bf + off)) = o;
  }
  for (int off = 32; off; off >>= 1) ss += __shfl_down(ss, off);
  if (lane == 0) *nrm = ss;
}

// ---------------- k_scc: bx<100 sc/cc; bx [100,132) fused sup x sub distances
// (32 blocks, 64 sup-rows x 128 sub-cols each, 4 waves, acc[2][4]);
// bx [132,532): Mt reduce+convert: Bf[o][k] = f2bf(-2 * sum_jc MtF[jc][o][k])
__global__ __launch_bounds__(256) void k_scc(const float* __restrict__ W1,
    const float* __restrict__ b1, const float* __restrict__ W2,
    const float* __restrict__ b2, const float* __restrict__ xxsup,
    const float* __restrict__ yys, float* __restrict__ sc, float* __restrict__ cc,
    const u16* __restrict__ sups, const u16* __restrict__ subs,
    const float* __restrict__ MtF, u16* __restrict__ Bf,
    unsigned int* __restrict__ rowmin, unsigned int* __restrict__ colsup) {
  __shared__ __align__(16) u16 lA[64 * 64];
  __shared__ __align__(16) u16 lB[128 * 64];
  int bx = blockIdx.x;
  if (bx >= 132) {
    int o = bx - 132;            // 0..399
    for (int k = threadIdx.x; k < 512; k += 256) {
      float s = 0.f;
#pragma unroll
      for (int c = 0; c < 8; c++) s += MtF[((size_t)c * 400 + o) * 512 + k];
      Bf[bfoff(o, k)] = f2bf(-2.f * s);
    }
    return;
  }
  if (bx >= 100) {
    int bid = bx - 100;          // 0..31
    int cb = bid & 7;
    size_t arow0 = (size_t)(bid >> 3) * 64;
    const u16* B = subs + (size_t)cb * 128 * LATENT;
    floatx4 acc[2][4] = {};
    int t = threadIdx.x, wave = t >> 6, lane = t & 63;
    int l16 = lane & 15, qq = lane >> 4;
    int wm = (wave >> 1) * 32, wn = (wave & 1) * 64;
    int sq = (lane & 7) ^ (lane >> 3);
    const u16* Ab = sups + arow0 * LATENT;
    int soffA[2], soffB[4]; u16 *dA[2], *dB[4];
#pragma unroll
    for (int i = 0; i < 2; i++) {
      int s = i * 256 + t;
      soffA[i] = (s >> 3) * LATENT + sq * 8;
      dA[i] = lA + (i * 256 + wave * 64) * 8;
    }
#pragma unroll
    for (int i = 0; i < 4; i++) {
      int s = i * 256 + t;
      soffB[i] = (s >> 3) * LATENT + sq * 8;
      dB[i] = lB + (i * 256 + wave * 64) * 8;
    }
    for (int k0 = 0; k0 < LATENT; k0 += 64) {
#pragma unroll
      for (int i = 0; i < 2; i++) gload16(Ab + soffA[i] + k0, dA[i]);
#pragma unroll
      for (int i = 0; i < 4; i++) gload16(B  + soffB[i] + k0, dB[i]);
      __syncthreads();
#pragma unroll
      for (int ks = 0; ks < 2; ks++) {
        bf16x8 af[2], bvv[4];
        int sw = ((ks * 4 + qq) ^ (l16 & 7)) * 8;
#pragma unroll
        for (int f = 0; f < 2; f++)
          af[f]  = *(const bf16x8*)(lA + (wm + f * 16 + l16) * 64 + sw);
#pragma unroll
        for (int f = 0; f < 4; f++)
          bvv[f] = *(const bf16x8*)(lB + (wn + f * 16 + l16) * 64 + sw);
#pragma unroll
        for (int fm = 0; fm < 2; fm++)
#pragma unroll
          for (int fn = 0; fn < 4; fn++)
            acc[fm][fn] = mfma_bf16(af[fm], bvv[fn], acc[fm][fn]);
      }
      __syncthreads();
    }
    int colb = cb * 128 + wn + l16;
    float yv[4];
#pragma unroll
    for (int fn = 0; fn < 4; fn++) yv[fn] = yys[colb + fn * 16];
    float cmin[4] = {3.4e38f, 3.4e38f, 3.4e38f, 3.4e38f};
#pragma unroll
    for (int fm = 0; fm < 2; fm++) {
#pragma unroll
      for (int r = 0; r < 4; r++) {
        int row = (int)arow0 + wm + fm * 16 + qq * 4 + r;
        float xvv = xxsup[row];
        float rmin = 3.4e38f;
#pragma unroll
        for (int fn = 0; fn < 4; fn++) {
          float d = xvv - 2.0f * acc[fm][fn][r] + yv[fn];
          rmin = fminf(rmin, d);
          cmin[fn] = fminf(cmin[fn], d);
        }
        for (int off = 1; off < 16; off <<= 1) rmin = fminf(rmin, __shfl_xor(rmin, off));
        if (l16 == 0) atomicMin(rowmin + BATCH + row, __float_as_uint(rmin));
      }
    }
#pragma unroll
    for (int fn = 0; fn < 4; fn++) {
      float v = cmin[fn];
      v = fminf(v, __shfl_xor(v, 16));
      v = fminf(v, __shfl_xor(v, 32));
      if (qq == 0) atomicMin(colsup + colb + fn * 16, __float_as_uint(v));
    }
    return;
  }
  int wave = threadIdx.x >> 6, lane = threadIdx.x & 63;
  int o = bx * 4 + wave;
  if (o >= 400) return;
  int n; const float* Wr; const float* yy;
  if (o < 200) { n = NSUP; Wr = W1 + (size_t)o * NSUP; yy = xxsup; }
  else         { n = NSUB; Wr = W2 + (size_t)(o - 200) * NSUB; yy = yys; }
  float s = 0.f, c = 0.f;
  for (int j = lane; j < n; j += 64) { float w = Wr[j]; s += w; c += w * yy[j]; }
  for (int off = 32; off; off >>= 1) { s += __shfl_down(s, off); c += __shfl_down(c, off); }
  if (lane == 0) { sc[o] = s; cc[o] = c + ((o < 200) ? b1[o] : b2[o - 200]); }
}

// ---------------- THE kernel: 64-row A tile (64 KB LDS), 512 threads / 8 waves, each
// wave one 64-col strip (N_w=64, acc[4][4]), 3 phases of 512 cols. Grid 512.
// KEY: __launch_bounds__(512, 2) -- the 2nd arg caps the COMPILER at 128 regs (this
// body needs ~108, proven R10); runtime occupancy is resource-determined: 2 blocks/CU
// (2x64KB LDS, 4x108 <= 512 regs/SIMD) = 4 waves/SIMD. R13's plan without its (512,4)
// 64-reg cap that caused the spill. Per-CU A-LDS and B traffic identical to R10.
__global__ __launch_bounds__(512, 2) void k_gemm_x(const float* __restrict__ x,
    const u16* __restrict__ Bf, const float* __restrict__ yys,
    const float* __restrict__ sc, const float* __restrict__ cc,
    float* __restrict__ out, unsigned int* __restrict__ rowmin,
    unsigned int* __restrict__ colx) {
  __shared__ __align__(16) u16 lA[64 * 512];   // 64 KB, 16B-chunk XOR-8 swizzle
  __shared__ float lxx[64];
  int t = threadIdx.x, wave = t >> 6, lane = t & 63;
  int l16 = lane & 15, qq = lane >> 4;
  int wc = wave;                               // 8 col-strips, all waves share 64 rows
  size_t arow0 = (size_t)blockIdx.x * 64;

  // ---- stage A: fp32 -> bf16 LDS (swizzled) + row sum-of-squares (8 waves x 8 rows)
  const float* Ab = x + arow0 * LATENT;
#pragma unroll
  for (int i = 0; i < 8; i++) {
    int row = i * 8 + wave;
    const float* s = Ab + (size_t)row * LATENT + lane * 8;
    float4 v0 = ((const float4*)s)[0];
    float4 v1 = ((const float4*)s)[1];
    float ss = v0.x*v0.x + v0.y*v0.y + v0.z*v0.z + v0.w*v0.w
             + v1.x*v1.x + v1.y*v1.y + v1.z*v1.z + v1.w*v1.w;
    uint4 o;
    o.x = (unsigned)f2bf(v0.x) | ((unsigned)f2bf(v0.y) << 16);
    o.y = (unsigned)f2bf(v0.z) | ((unsigned)f2bf(v0.w) << 16);
    o.z = (unsigned)f2bf(v1.x) | ((unsigned)f2bf(v1.y) << 16);
    o.w = (unsigned)f2bf(v1.z) | ((unsigned)f2bf(v1.w) << 16);
    *((uint4*)(lA + ((row * 64) + (lane ^ (row & 7))) * 8)) = o;
    for (int off = 32; off; off >>= 1) ss += __shfl_down(ss, off);
    if (lane == 0) lxx[row] = ss;
  }
  __syncthreads();   // the ONLY barrier

#pragma unroll 1
  for (int p = 0; p < 3; p++) {            // 3 phases of 512 cols; wave strip = 64 cols
    floatx4 acc[4][4] = {};
    const u16* Bw = Bf + (size_t)(p * 32 + wc * 4) * 8192 + lane * 8;
#pragma unroll 2
    for (int k0 = 0; k0 < LATENT; k0 += 64) {
      bf16x8 bv[4][2];
#pragma unroll
      for (int nf = 0; nf < 4; nf++)
#pragma unroll
        for (int ks = 0; ks < 2; ks++)
          bv[nf][ks] = *(const bf16x8*)(Bw + nf * 8192 + k0 * 16 + ks * 512);
#pragma unroll
      for (int ks = 0; ks < 2; ks++) {
        bf16x8 a[4];
#pragma unroll
        for (int mf = 0; mf < 4; mf++) {
          int row = mf * 16 + l16;
          int kc = (k0 >> 3) + ks * 4 + qq;
          a[mf] = *(const bf16x8*)(lA + ((row * 64) + (kc ^ (row & 7))) * 8);
        }
#pragma unroll
        for (int mf = 0; mf < 4; mf++)
#pragma unroll
          for (int nf = 0; nf < 4; nf++)
            acc[mf][nf] = mfma_bf16(a[mf], bv[nf][ks], acc[mf][nf]);
      }
    }
    // per-phase epilogue; xx re-read from LDS (no state lives across the K-loop)
    float xr[4][4];
#pragma unroll
    for (int mf = 0; mf < 4; mf++)
#pragma unroll
      for (int r = 0; r < 4; r++) xr[mf][r] = lxx[mf * 16 + qq * 4 + r];
    if (p == 0) {
      // classifier heads: out = acc + xx*sc + cc (cols wc*64.., valid < 400)
      int colbase = wc * 64;
#pragma unroll
      for (int nf = 0; nf < 4; nf++) {
        int c = colbase + nf * 16 + l16;
        if (c < 400) {
          float scv = sc[c], ccv = cc[c];
#pragma unroll
          for (int mf = 0; mf < 4; mf++)
#pragma unroll
            for (int r = 0; r < 4; r++) {
              size_t row = arow0 + mf * 16 + qq * 4 + r;
              float v = acc[mf][nf][r] + xr[mf][r] * scv + ccv;
              size_t idx = (c < 200) ? (SUP_OFF + row * NOUT + c)
                                     : (row * NOUT + (c - 200));
              out[idx] = v;
            }
        }
      }
    } else {
      // distance mins: d = xx - 2*acc + yy (sub cols); flush row/col mins per phase
      int colbase = (p - 1) * 512 + wc * 64;
      float rm[4][4];
#pragma unroll
      for (int mf = 0; mf < 4; mf++)
#pragma unroll
        for (int r = 0; r < 4; r++) rm[mf][r] = 3.4e38f;
#pragma unroll
      for (int nf = 0; nf < 4; nf++) {
        int cs = colbase + nf * 16 + l16;
        float yv = yys[cs];
        float cmin = 3.4e38f;
#pragma unroll
        for (int mf = 0; mf < 4; mf++)
#pragma unroll
          for (int r = 0; r < 4; r++) {
            float d = xr[mf][r] - 2.0f * acc[mf][nf][r] + yv;
            rm[mf][r] = fminf(rm[mf][r], d);
            cmin = fminf(cmin, d);
          }
        cmin = fminf(cmin, __shfl_xor(cmin, 16));
        cmin = fminf(cmin, __shfl_xor(cmin, 32));
        if (qq == 0) atomicMin(colx + cs, __float_as_uint(cmin));
      }
#pragma unroll
      for (int mf = 0; mf < 4; mf++)
#pragma unroll
        for (int r = 0; r < 4; r++) {
          float v = rm[mf][r];
          v = fminf(v, __shfl_xor(v, 1));
          v = fminf(v, __shfl_xor(v, 2));
          v = fminf(v, __shfl_xor(v, 4));
          v = fminf(v, __shfl_xor(v, 8));
          if (l16 == 0)
            atomicMin(rowmin + arow0 + mf * 16 + qq * 4 + r, __float_as_uint(v));
        }
    }
  }
}

// ---------------- parallel means of mins -> r1,r2,r3,r4 (atomicAdd partials)
__global__ __launch_bounds__(256) void k_final2(const unsigned int* __restrict__ rowmin,
    const unsigned int* __restrict__ colx, const unsigned int* __restrict__ colsup,
    float* __restrict__ out4) {
  int bx = blockIdx.x, t = threadIdx.x;
  const unsigned int* src; int n; float scale; int slot;
  if (bx < 32)      { src = rowmin + bx * 1024; n = 1024; scale = 1.f / BATCH; slot = 1; }
  else if (bx == 32){ src = colx;               n = 1024; scale = 1.f / NSUB;  slot = 0; }
  else if (bx == 33){ src = rowmin + BATCH;     n = 256;  scale = 1.f / NSUP;  slot = 2; }
  else              { src = colsup;             n = 1024; scale = 1.f / NSUB;  slot = 3; }
  float s = 0.f;
  for (int i = t; i < n; i += 256) s += __uint_as_float(src[i]);
  __shared__ float red[4];
  for (int off = 32; off; off >>= 1) s += __shfl_down(s, off);
  if ((t & 63) == 0) red[t >> 6] = s;
  __syncthreads();
  if (t == 0) atomicAdd(out4 + slot, (red[0] + red[1] + red[2] + red[3]) * scale);
}

extern "C" void kernel_launch(void* const* d_in, const int* in_sizes, int n_in,
                              void* d_out, int out_size, void* d_ws, size_t ws_size,
                              hipStream_t stream) {
  const float* x   = (const float*)d_in[0];
  const float* sup = (const float*)d_in[1];
  const float* sub = (const float*)d_in[2];
  const float* W1  = (const float*)d_in[3];
  const float* b1  = (const float*)d_in[4];
  const float* W2  = (const float*)d_in[5];
  const float* b2  = (const float*)d_in[6];
  float* out = (float*)d_out;

  char* p = (char*)d_ws;
  u16* Bf    = (u16*)p;            p += (size_t)(512 + NSUB) * LATENT * 2; // frag-major (Mt ++ sub)
  u16* subs  = (u16*)p;            p += (size_t)NSUB * LATENT * 2;         // row-major for sup part
  u16* sups  = (u16*)p;            p += (size_t)NSUP * LATENT * 2;
  float* xxsup = (float*)p;        p += NSUP * 4;
  float* yys   = (float*)p;        p += NSUB * 4;
  float* sc    = (float*)p;        p += 512 * 4;
  float* cc    = (float*)p;        p += 512 * 4;
  unsigned int* rowmin = (unsigned int*)p; p += (size_t)(BATCH + NSUP) * 4;
  unsigned int* colx   = (unsigned int*)p; p += (size_t)NSUB * 4;
  unsigned int* colsup = (unsigned int*)p; p += (size_t)NSUB * 4;
  float* MtF   = (float*)p;        p += (size_t)8 * 400 * 512 * 4;         // Mt j-chunk partials

  float* out4 = out + 2 * SUP_OFF;

  hipLaunchKernelGGL(k_setup, dim3(1286), dim3(256), 0, stream,
                     sup, sub, W1, W2, sups, subs, Bf, MtF, xxsup, yys, rowmin, out4);
  hipLaunchKernelGGL(k_scc, dim3(532), dim3(256), 0, stream,
                     W1, b1, W2, b2, xxsup, yys, sc, cc, sups, subs, MtF, Bf,
                     rowmin, colsup);
  hipLaunchKernelGGL(k_gemm_x, dim3(BATCH / 64), dim3(512), 0, stream,
                     x, Bf, yys, sc, cc, out, rowmin, colx);
  hipLaunchKernelGGL(k_final2, dim3(35), dim3(256), 0, stream, rowmin, colx, colsup, out4);
}

// Round 16
// 107.135 us; speedup vs baseline: 1.3945x; 1.3945x over previous
//
#include <hip/hip_runtime.h>
#include <stdint.h>

#define BATCH   32768
#define NSUP    256
#define NSUB    1024
#define LATENT  512
#define NOUT    200
#define SUP_OFF ((size_t)BATCH * NOUT)  // sup_out offset in d_out

typedef unsigned short u16;
typedef __attribute__((ext_vector_type(8))) __bf16 bf16x8;
typedef __attribute__((ext_vector_type(4))) float  floatx4;

typedef const __attribute__((address_space(1))) void* gptr_t;
typedef __attribute__((address_space(3))) void* sptr_t;

__device__ __forceinline__ void gload16(const void* g, void* l) {
  __builtin_amdgcn_global_load_lds((gptr_t)g, (sptr_t)l, 16, 0, 0);
}

__device__ __forceinline__ floatx4 mfma_bf16(bf16x8 a, bf16x8 b, floatx4 c) {
  return __builtin_amdgcn_mfma_f32_16x16x32_bf16(a, b, c, 0, 0, 0);
}

__device__ __forceinline__ u16 f2bf(float f) {
  unsigned int u = __float_as_uint(f);
  u += 0x7FFFu + ((u >> 16) & 1u);   // RNE; inputs finite
  return (u16)(u >> 16);
}

// Bf frag-major layout: col c, k -> group g=c>>4, kc=k>>5, lane=((k>>3)&3)*16 + (c&15), e=k&7
// u16 offset = g*8192 + kc*512 + lane*8 + e. A wave's bv load (16 cols x 32 k) is one
// contiguous 1KB block: lane i reads 16B at base + i*16. No segment splintering.
__device__ __forceinline__ size_t bfoff(int c, int k) {
  return (size_t)(c >> 4) * 8192 + (size_t)((k >> 5) * 512)
       + (size_t)((((k >> 3) & 3) * 16 + (c & 15)) * 8) + (size_t)(k & 7);
}

// ---------------- setup kernel:
// bx [0,320): convert 4 rows each (sup rows 0..255, then sub 0..1023); sub rows written
//   row-major (subs) + frag-major (Bf cols 512..1535)
// bx [320,457): init 35072 min-uints to +inf; bx 457: zero out4
// bx [458,1258): Mt PARTIALS: 800 blocks = 50 o-groups x 2 k-halves x 8 j-chunks;
//   each computes sum_{j in chunk} W[o,j] P[j,k] -> MtF[jc][o][k] (f32, disjoint writes)
// bx [1258,1286): zero Bf cols 400..511
__global__ __launch_bounds__(256) void k_setup(const float* __restrict__ sup,
    const float* __restrict__ sub, const float* __restrict__ W1,
    const float* __restrict__ W2, u16* __restrict__ sups, u16* __restrict__ subs,
    u16* __restrict__ Bf, float* __restrict__ MtF, float* __restrict__ xxsup,
    float* __restrict__ yys, unsigned int* __restrict__ minbuf,
    float* __restrict__ out4) {
  __shared__ float lw[8 * 128];
  int bx = blockIdx.x;
  if (bx >= 458) {
    int idx = bx - 458;
    if (idx >= 800) {            // zero blocks for Bf cols 400..511
      int z = idx - 800;         // 0..27
      int k = (z & 1) * 256 + threadIdx.x;
      int o0 = 400 + (z >> 1) * 8;
      for (int oo = 0; oo < 8; oo++) Bf[bfoff(o0 + oo, k)] = 0;
      return;
    }
    int jc = idx & 7;
    int kb = (idx >> 3) & 1;
    int o0 = (idx >> 4) * 8;     // 0,8,...,392
    int k  = kb * 256 + threadIdx.x;
    const float* P; const float* W; int n, ow, nqs;
    if (o0 < 200) { P = sup; W = W1; n = NSUP;  ow = o0;       nqs = 5; }
    else          { P = sub; W = W2; n = NSUB;  ow = o0 - 200; nqs = 7; }
    int nq = 1 << nqs;           // 32 (sup) or 128 (sub)
    int j0 = jc * nq;
    for (int i = threadIdx.x; i < 8 * nq; i += 256) {
      int oo = i >> nqs, j = i & (nq - 1);
      lw[oo * 128 + j] = W[(size_t)(ow + oo) * n + j0 + j];
    }
    __syncthreads();
    float a[8] = {};
    for (int j = 0; j < nq; j += 8) {          // 8 loads in flight
      float pv[8];
#pragma unroll
      for (int u = 0; u < 8; u++) pv[u] = P[(size_t)(j0 + j + u) * LATENT + k];
#pragma unroll
      for (int oo = 0; oo < 8; oo++) {
        float acc = 0.f;
#pragma unroll
        for (int u = 0; u < 8; u++) acc += pv[u] * lw[oo * 128 + j + u];
        a[oo] += acc;
      }
    }
#pragma unroll
    for (int oo = 0; oo < 8; oo++)
      MtF[((size_t)jc * 400 + o0 + oo) * 512 + k] = a[oo];
    return;
  }
  if (bx >= 320) {
    if (bx == 457) { if (threadIdx.x < 4) out4[threadIdx.x] = 0.f; return; }
    int i = (bx - 320) * 256 + threadIdx.x;
    if (i < BATCH + NSUP + 2 * NSUB) minbuf[i] = 0x7F800000u;
    return;
  }
  int row  = bx * 4 + (threadIdx.x >> 6);
  int lane = threadIdx.x & 63;
  const float* src; u16* dst; float* nrm; int subrow = -1;
  if (row < NSUP) { src = sup + (size_t)row * LATENT; dst = sups + (size_t)row * LATENT; nrm = xxsup + row; }
  else { int r = row - NSUP; subrow = r; src = sub + (size_t)r * LATENT; dst = subs + (size_t)r * LATENT; nrm = yys + r; }
  const float* s = src + lane * 8;
  float4 v0 = ((const float4*)s)[0];
  float4 v1 = ((const float4*)s)[1];
  float ss = v0.x*v0.x + v0.y*v0.y + v0.z*v0.z + v0.w*v0.w
           + v1.x*v1.x + v1.y*v1.y + v1.z*v1.z + v1.w*v1.w;
  uint4 o;
  o.x = (unsigned)f2bf(v0.x) | ((unsigned)f2bf(v0.y) << 16);
  o.y = (unsigned)f2bf(v0.z) | ((unsigned)f2bf(v0.w) << 16);
  o.z = (unsigned)f2bf(v1.x) | ((unsigned)f2bf(v1.y) << 16);
  o.w = (unsigned)f2bf(v1.z) | ((unsigned)f2bf(v1.w) << 16);
  *((uint4*)(dst + lane * 8)) = o;
  if (subrow >= 0) {
    size_t off = (size_t)(32 + (subrow >> 4)) * 8192 + (size_t)((lane >> 2) * 512)
               + (size_t)((((lane & 3) * 16) + (subrow & 15)) * 8);
    *((uint4*)(Bf + off)) = o;
  }
  for (int off = 32; off; off >>= 1) ss += __shfl_down(ss, off);
  if (lane == 0) *nrm = ss;
}

// ---------------- k_scc: bx<100 sc/cc; bx [100,132) fused sup x sub distances
// (32 blocks, 64 sup-rows x 128 sub-cols each, 4 waves, acc[2][4]);
// bx [132,532): Mt reduce+convert: Bf[o][k] = f2bf(-2 * sum_jc MtF[jc][o][k])
__global__ __launch_bounds__(256) void k_scc(const float* __restrict__ W1,
    const float* __restrict__ b1, const float* __restrict__ W2,
    const float* __restrict__ b2, const float* __restrict__ xxsup,
    const float* __restrict__ yys, float* __restrict__ sc, float* __restrict__ cc,
    const u16* __restrict__ sups, const u16* __restrict__ subs,
    const float* __restrict__ MtF, u16* __restrict__ Bf,
    unsigned int* __restrict__ rowmin, unsigned int* __restrict__ colsup) {
  __shared__ __align__(16) u16 lA[64 * 64];
  __shared__ __align__(16) u16 lB[128 * 64];
  int bx = blockIdx.x;
  if (bx >= 132) {
    int o = bx - 132;            // 0..399
    for (int k = threadIdx.x; k < 512; k += 256) {
      float s = 0.f;
#pragma unroll
      for (int c = 0; c < 8; c++) s += MtF[((size_t)c * 400 + o) * 512 + k];
      Bf[bfoff(o, k)] = f2bf(-2.f * s);
    }
    return;
  }
  if (bx >= 100) {
    int bid = bx - 100;          // 0..31
    int cb = bid & 7;
    size_t arow0 = (size_t)(bid >> 3) * 64;
    const u16* B = subs + (size_t)cb * 128 * LATENT;
    floatx4 acc[2][4] = {};
    int t = threadIdx.x, wave = t >> 6, lane = t & 63;
    int l16 = lane & 15, qq = lane >> 4;
    int wm = (wave >> 1) * 32, wn = (wave & 1) * 64;
    int sq = (lane & 7) ^ (lane >> 3);
    const u16* Ab = sups + arow0 * LATENT;
    int soffA[2], soffB[4]; u16 *dA[2], *dB[4];
#pragma unroll
    for (int i = 0; i < 2; i++) {
      int s = i * 256 + t;
      soffA[i] = (s >> 3) * LATENT + sq * 8;
      dA[i] = lA + (i * 256 + wave * 64) * 8;
    }
#pragma unroll
    for (int i = 0; i < 4; i++) {
      int s = i * 256 + t;
      soffB[i] = (s >> 3) * LATENT + sq * 8;
      dB[i] = lB + (i * 256 + wave * 64) * 8;
    }
    for (int k0 = 0; k0 < LATENT; k0 += 64) {
#pragma unroll
      for (int i = 0; i < 2; i++) gload16(Ab + soffA[i] + k0, dA[i]);
#pragma unroll
      for (int i = 0; i < 4; i++) gload16(B  + soffB[i] + k0, dB[i]);
      __syncthreads();
#pragma unroll
      for (int ks = 0; ks < 2; ks++) {
        bf16x8 af[2], bvv[4];
        int sw = ((ks * 4 + qq) ^ (l16 & 7)) * 8;
#pragma unroll
        for (int f = 0; f < 2; f++)
          af[f]  = *(const bf16x8*)(lA + (wm + f * 16 + l16) * 64 + sw);
#pragma unroll
        for (int f = 0; f < 4; f++)
          bvv[f] = *(const bf16x8*)(lB + (wn + f * 16 + l16) * 64 + sw);
#pragma unroll
        for (int fm = 0; fm < 2; fm++)
#pragma unroll
          for (int fn = 0; fn < 4; fn++)
            acc[fm][fn] = mfma_bf16(af[fm], bvv[fn], acc[fm][fn]);
      }
      __syncthreads();
    }
    int colb = cb * 128 + wn + l16;
    float yv[4];
#pragma unroll
    for (int fn = 0; fn < 4; fn++) yv[fn] = yys[colb + fn * 16];
    float cmin[4] = {3.4e38f, 3.4e38f, 3.4e38f, 3.4e38f};
#pragma unroll
    for (int fm = 0; fm < 2; fm++) {
#pragma unroll
      for (int r = 0; r < 4; r++) {
        int row = (int)arow0 + wm + fm * 16 + qq * 4 + r;
        float xvv = xxsup[row];
        float rmin = 3.4e38f;
#pragma unroll
        for (int fn = 0; fn < 4; fn++) {
          float d = xvv - 2.0f * acc[fm][fn][r] + yv[fn];
          rmin = fminf(rmin, d);
          cmin[fn] = fminf(cmin[fn], d);
        }
        for (int off = 1; off < 16; off <<= 1) rmin = fminf(rmin, __shfl_xor(rmin, off));
        if (l16 == 0) atomicMin(rowmin + BATCH + row, __float_as_uint(rmin));
      }
    }
#pragma unroll
    for (int fn = 0; fn < 4; fn++) {
      float v = cmin[fn];
      v = fminf(v, __shfl_xor(v, 16));
      v = fminf(v, __shfl_xor(v, 32));
      if (qq == 0) atomicMin(colsup + colb + fn * 16, __float_as_uint(v));
    }
    return;
  }
  int wave = threadIdx.x >> 6, lane = threadIdx.x & 63;
  int o = bx * 4 + wave;
  if (o >= 400) return;
  int n; const float* Wr; const float* yy;
  if (o < 200) { n = NSUP; Wr = W1 + (size_t)o * NSUP; yy = xxsup; }
  else         { n = NSUB; Wr = W2 + (size_t)(o - 200) * NSUB; yy = yys; }
  float s = 0.f, c = 0.f;
  for (int j = lane; j < n; j += 64) { float w = Wr[j]; s += w; c += w * yy[j]; }
  for (int off = 32; off; off >>= 1) { s += __shfl_down(s, off); c += __shfl_down(c, off); }
  if (lane == 0) { sc[o] = s; cc[o] = c + ((o < 200) ? b1[o] : b2[o - 200]); }
}

// ---------------- THE kernel (R10/R12 verbatim): 128-row A tile (128 KB LDS), 512
// threads / 8 waves (2 row-halves x 4 col-strips), per-wave tile 64x64 (acc[4][4]),
// (512,2). Grid 256 = 1 block/CU. Proven 82 us / VGPR 108 / clean counters. FROZEN:
// all neighbor configs measured worse (tile R9/R11, TLP R4/R13/R15, pipeline R6).
__global__ __launch_bounds__(512, 2) void k_gemm_x(const float* __restrict__ x,
    const u16* __restrict__ Bf, const float* __restrict__ yys,
    const float* __restrict__ sc, const float* __restrict__ cc,
    float* __restrict__ out, unsigned int* __restrict__ rowmin,
    unsigned int* __restrict__ colx) {
  __shared__ __align__(16) u16 lA[128 * 512];   // 128 KB, 16B-chunk XOR-8 swizzle
  __shared__ float lxx[128];
  int t = threadIdx.x, wave = t >> 6, lane = t & 63;
  int l16 = lane & 15, qq = lane >> 4;
  int wr = wave >> 2, wc = wave & 3;
  size_t arow0 = (size_t)blockIdx.x * 128;

  // ---- stage A: fp32 -> bf16 LDS (swizzled) + row sum-of-squares (8 waves x 16 rows)
  const float* Ab = x + arow0 * LATENT;
#pragma unroll
  for (int i = 0; i < 16; i++) {
    int row = i * 8 + wave;
    const float* s = Ab + (size_t)row * LATENT + lane * 8;
    float4 v0 = ((const float4*)s)[0];
    float4 v1 = ((const float4*)s)[1];
    float ss = v0.x*v0.x + v0.y*v0.y + v0.z*v0.z + v0.w*v0.w
             + v1.x*v1.x + v1.y*v1.y + v1.z*v1.z + v1.w*v1.w;
    uint4 o;
    o.x = (unsigned)f2bf(v0.x) | ((unsigned)f2bf(v0.y) << 16);
    o.y = (unsigned)f2bf(v0.z) | ((unsigned)f2bf(v0.w) << 16);
    o.z = (unsigned)f2bf(v1.x) | ((unsigned)f2bf(v1.y) << 16);
    o.w = (unsigned)f2bf(v1.z) | ((unsigned)f2bf(v1.w) << 16);
    *((uint4*)(lA + ((row * 64) + (lane ^ (row & 7))) * 8)) = o;
    for (int off = 32; off; off >>= 1) ss += __shfl_down(ss, off);
    if (lane == 0) lxx[row] = ss;
  }
  __syncthreads();   // the ONLY barrier

  float xv[4][4];
#pragma unroll
  for (int mf = 0; mf < 4; mf++)
#pragma unroll
    for (int r = 0; r < 4; r++) xv[mf][r] = lxx[wr * 64 + mf * 16 + qq * 4 + r];
  float rmreg[4][4];
#pragma unroll
  for (int mf = 0; mf < 4; mf++)
#pragma unroll
    for (int r = 0; r < 4; r++) rmreg[mf][r] = 3.4e38f;

#pragma unroll 1
  for (int p = 0; p < 6; p++) {            // 6 phases of 256 cols; wave strip = 64 cols
    floatx4 acc[4][4] = {};
    const u16* Bw = Bf + (size_t)(p * 16 + wc * 4) * 8192 + lane * 8;
#pragma unroll 2
    for (int k0 = 0; k0 < LATENT; k0 += 64) {
      bf16x8 bv[4][2];
#pragma unroll
      for (int nf = 0; nf < 4; nf++)
#pragma unroll
        for (int ks = 0; ks < 2; ks++)
          bv[nf][ks] = *(const bf16x8*)(Bw + nf * 8192 + k0 * 16 + ks * 512);
#pragma unroll
      for (int ks = 0; ks < 2; ks++) {
        bf16x8 a[4];
#pragma unroll
        for (int mf = 0; mf < 4; mf++) {
          int row = wr * 64 + mf * 16 + l16;
          int kc = (k0 >> 3) + ks * 4 + qq;
          a[mf] = *(const bf16x8*)(lA + ((row * 64) + (kc ^ (row & 7))) * 8);
        }
#pragma unroll
        for (int mf = 0; mf < 4; mf++)
#pragma unroll
          for (int nf = 0; nf < 4; nf++)
            acc[mf][nf] = mfma_bf16(a[mf], bv[nf][ks], acc[mf][nf]);
      }
    }
    if (p < 2) {
      // classifier heads: out = acc + xx*sc + cc (cols p*256 + wc*64 .., valid < 400)
      int colbase = p * 256 + wc * 64;
#pragma unroll
      for (int nf = 0; nf < 4; nf++) {
        int c = colbase + nf * 16 + l16;
        if (c < 400) {
          float scv = sc[c], ccv = cc[c];
#pragma unroll
          for (int mf = 0; mf < 4; mf++)
#pragma unroll
            for (int r = 0; r < 4; r++) {
              size_t row = arow0 + wr * 64 + mf * 16 + qq * 4 + r;
              float v = acc[mf][nf][r] + xv[mf][r] * scv + ccv;
              size_t idx = (c < 200) ? (SUP_OFF + row * NOUT + c)
                                     : (row * NOUT + (c - 200));
              out[idx] = v;
            }
        }
      }
    } else {
      // distance mins: d = xx - 2*acc + yy (sub cols)
      int colbase = p * 256 + wc * 64 - 512;
#pragma unroll
      for (int nf = 0; nf < 4; nf++) {
        int cs = colbase + nf * 16 + l16;
        float yv = yys[cs];
        float cmin = 3.4e38f;
#pragma unroll
        for (int mf = 0; mf < 4; mf++)
#pragma unroll
          for (int r = 0; r < 4; r++) {
            float d = xv[mf][r] - 2.0f * acc[mf][nf][r] + yv;
            rmreg[mf][r] = fminf(rmreg[mf][r], d);
            cmin = fminf(cmin, d);
          }
        cmin = fminf(cmin, __shfl_xor(cmin, 16));
        cmin = fminf(cmin, __shfl_xor(cmin, 32));
        if (qq == 0) atomicMin(colx + cs, __float_as_uint(cmin));
      }
    }
  }
  // row mins: reduce across the 16 l16-lanes (cols), merge waves/blocks via atomics
#pragma unroll
  for (int mf = 0; mf < 4; mf++)
#pragma unroll
    for (int r = 0; r < 4; r++) {
      float v = rmreg[mf][r];
      v = fminf(v, __shfl_xor(v, 1));
      v = fminf(v, __shfl_xor(v, 2));
      v = fminf(v, __shfl_xor(v, 4));
      v = fminf(v, __shfl_xor(v, 8));
      if (l16 == 0)
        atomicMin(rowmin + arow0 + wr * 64 + mf * 16 + qq * 4 + r, __float_as_uint(v));
    }
}

// ---------------- parallel means of mins -> r1,r2,r3,r4 (atomicAdd partials)
__global__ __launch_bounds__(256) void k_final2(const unsigned int* __restrict__ rowmin,
    const unsigned int* __restrict__ colx, const unsigned int* __restrict__ colsup,
    float* __restrict__ out4) {
  int bx = blockIdx.x, t = threadIdx.x;
  const unsigned int* src; int n; float scale; int slot;
  if (bx < 32)      { src = rowmin + bx * 1024; n = 1024; scale = 1.f / BATCH; slot = 1; }
  else if (bx == 32){ src = colx;               n = 1024; scale = 1.f / NSUB;  slot = 0; }
  else if (bx == 33){ src = rowmin + BATCH;     n = 256;  scale = 1.f / NSUP;  slot = 2; }
  else              { src = colsup;             n = 1024; scale = 1.f / NSUB;  slot = 3; }
  float s = 0.f;
  for (int i = t; i < n; i += 256) s += __uint_as_float(src[i]);
  __shared__ float red[4];
  for (int off = 32; off; off >>= 1) s += __shfl_down(s, off);
  if ((t & 63) == 0) red[t >> 6] = s;
  __syncthreads();
  if (t == 0) atomicAdd(out4 + slot, (red[0] + red[1] + red[2] + red[3]) * scale);
}

extern "C" void kernel_launch(void* const* d_in, const int* in_sizes, int n_in,
                              void* d_out, int out_size, void* d_ws, size_t ws_size,
                              hipStream_t stream) {
  const float* x   = (const float*)d_in[0];
  const float* sup = (const float*)d_in[1];
  const float* sub = (const float*)d_in[2];
  const float* W1  = (const float*)d_in[3];
  const float* b1  = (const float*)d_in[4];
  const float* W2  = (const float*)d_in[5];
  const float* b2  = (const float*)d_in[6];
  float* out = (float*)d_out;

  char* p = (char*)d_ws;
  u16* Bf    = (u16*)p;            p += (size_t)(512 + NSUB) * LATENT * 2; // frag-major (Mt ++ sub)
  u16* subs  = (u16*)p;            p += (size_t)NSUB * LATENT * 2;         // row-major for sup part
  u16* sups  = (u16*)p;            p += (size_t)NSUP * LATENT * 2;
  float* xxsup = (float*)p;        p += NSUP * 4;
  float* yys   = (float*)p;        p += NSUB * 4;
  float* sc    = (float*)p;        p += 512 * 4;
  float* cc    = (float*)p;        p += 512 * 4;
  unsigned int* rowmin = (unsigned int*)p; p += (size_t)(BATCH + NSUP) * 4;
  unsigned int* colx   = (unsigned int*)p; p += (size_t)NSUB * 4;
  unsigned int* colsup = (unsigned int*)p; p += (size_t)NSUB * 4;
  float* MtF   = (float*)p;        p += (size_t)8 * 400 * 512 * 4;         // Mt j-chunk partials

  float* out4 = out + 2 * SUP_OFF;

  hipLaunchKernelGGL(k_setup, dim3(1286), dim3(256), 0, stream,
                     sup, sub, W1, W2, sups, subs, Bf, MtF, xxsup, yys, rowmin, out4);
  hipLaunchKernelGGL(k_scc, dim3(532), dim3(256), 0, stream,
                     W1, b1, W2, b2, xxsup, yys, sc, cc, sups, subs, MtF, Bf,
                     rowmin, colsup);
  hipLaunchKernelGGL(k_gemm_x, dim3(BATCH / 128), dim3(512), 0, stream,
                     x, Bf, yys, sc, cc, out, rowmin, colx);
  hipLaunchKernelGGL(k_final2, dim3(35), dim3(256), 0, stream, rowmin, colx, colsup, out4);
}